// Round 1
// 3741.995 us; speedup vs baseline: 1.5697x; 1.5697x over previous
//
#include <hip/hip_runtime.h>

typedef unsigned short ushort_t;
typedef unsigned int   uint32;
typedef __attribute__((ext_vector_type(8))) short short8;   // 8 x bf16 (4 VGPRs)
typedef __attribute__((ext_vector_type(4))) float floatx4;  // MFMA 16x16 accum

#define B_    32
#define T_    512
#define H_    1024
#define G4_   4096
#define HSEQ_ (B_*T_*H_)     // 16777216

#define NBLK 64

// ---- ws layout, xproj path (requires ws_size >= WS_NEED) ----
#define XPROJ_OFF 0ul                 // bf16 [16384][4096] = 134217728
#define WTIH_OFF  134217728ul         // bf16 [4096][1024]  = 8388608
#define WTHH_OFF  142606336ul         // bf16 [4096][1024]  = 8388608
#define H0X_OFF   150994944ul         // bf16 frag-layout   = 65536
#define H1X_OFF   151060480ul         // bf16 frag-layout   = 65536
#define FLAGS_OFF 151126016ul         // 64 x uint32, 64B-padded = 4096
#define WS_NEED   151130112ul

// ---- ws layout, fallback path (R4) ----
#define H0_OFF  0ul
#define H1_OFF  65536ul
#define CTR_OFF 131072ul

__device__ __forceinline__ ushort_t f2b_rne(float f) {
    uint32 u = __float_as_uint(f);
    u += 0x7fffu + ((u >> 16) & 1u);      // round-to-nearest-even
    return (ushort_t)(u >> 16);
}
__device__ __forceinline__ float b2f(ushort_t u) { return __uint_as_float(((uint32)u) << 16); }
__device__ __forceinline__ float sigm(float x)  { return 1.f / (1.f + __expf(-x)); }
__device__ __forceinline__ float tanh_(float x) { return 1.f - 2.f / (__expf(2.f * x) + 1.f); }

// ---------------------------------------------------------------------------
// Transpose+convert: in fp32 [1024 k][4096 n] -> out bf16 [4096 n][1024 k].
// ---------------------------------------------------------------------------
__global__ void transpose_cvt(const float* __restrict__ in, ushort_t* __restrict__ out)
{
    const int id = blockIdx.x * 256 + threadIdx.x;    // 524288 total
    const int n  = id & 4095;
    const int k0 = (id >> 12) * 8;
    union { ushort_t v[8]; uint4 q; } r;
#pragma unroll
    for (int j = 0; j < 8; j++)
        r.v[j] = f2b_rne(in[(size_t)(k0 + j) * G4_ + n]);
    *(uint4*)(out + (size_t)n * 1024 + k0) = r.q;
}

// ---------------------------------------------------------------------------
// xproj GEMM: xproj[m][n] = bf16( sum_k x[m][k]*W_ih[k][n] + bias[n] )
// ---------------------------------------------------------------------------
__launch_bounds__(256, 2)
__global__ void gemm_xproj(const float* __restrict__ A, const ushort_t* __restrict__ Bt,
                           const float* __restrict__ bias, ushort_t* __restrict__ C)
{
    __shared__ ushort_t As[128 * 32];
    __shared__ ushort_t Bs[128 * 32];
    const int tid = threadIdx.x;
    const int wave = tid >> 6, lane = tid & 63, l16 = lane & 15, quad = lane >> 4;
    const int wm = (wave >> 1) * 64, wn = (wave & 1) * 64;
    const int m0 = blockIdx.y * 128, n0 = blockIdx.x * 128;
    const int r = tid >> 2;               // 0..63 (staging row)
    const int kp = (tid & 3) * 8;         // 0..24 step 8

    floatx4 acc[4][4];
#pragma unroll
    for (int i = 0; i < 4; i++)
#pragma unroll
        for (int j = 0; j < 4; j++) acc[i][j] = (floatx4){0.f, 0.f, 0.f, 0.f};

    for (int kk = 0; kk < 1024; kk += 32) {
#pragma unroll
        for (int h = 0; h < 2; h++) {
            const float* ap = A + (size_t)(m0 + r + h * 64) * 1024 + kk + kp;
            const uint4 u0 = *(const uint4*)ap;
            const uint4 u1 = *(const uint4*)(ap + 4);
            uint4 p;
            p.x = __builtin_amdgcn_perm(u0.y, u0.x, 0x07060302u);
            p.y = __builtin_amdgcn_perm(u0.w, u0.z, 0x07060302u);
            p.z = __builtin_amdgcn_perm(u1.y, u1.x, 0x07060302u);
            p.w = __builtin_amdgcn_perm(u1.w, u1.z, 0x07060302u);
            *(uint4*)&As[(r + h * 64) * 32 + kp] = p;
        }
        const ushort_t* bp = Bt + (size_t)(n0 + r) * 1024 + kk + kp;
        *(uint4*)&Bs[r * 32 + kp]        = *(const uint4*)bp;
        *(uint4*)&Bs[(r + 64) * 32 + kp] = *(const uint4*)(bp + 64 * 1024);
        __syncthreads();

        short8 af[4], bfr[4];
#pragma unroll
        for (int i = 0; i < 4; i++) af[i]  = *(const short8*)&As[(wm + i * 16 + l16) * 32 + quad * 8];
#pragma unroll
        for (int j = 0; j < 4; j++) bfr[j] = *(const short8*)&Bs[(wn + j * 16 + l16) * 32 + quad * 8];
#pragma unroll
        for (int i = 0; i < 4; i++)
#pragma unroll
            for (int j = 0; j < 4; j++)
                acc[i][j] = __builtin_amdgcn_mfma_f32_16x16x32_bf16(af[i], bfr[j], acc[i][j], 0, 0, 0);
        __syncthreads();
    }

#pragma unroll
    for (int i = 0; i < 4; i++) {
        const int gm = m0 + wm + i * 16 + quad * 4;
#pragma unroll
        for (int j = 0; j < 4; j++) {
            const int gn = n0 + wn + j * 16 + l16;
            const float bv = bias[gn];
#pragma unroll
            for (int rr = 0; rr < 4; rr++)
                C[(size_t)(gm + rr) * G4_ + gn] = f2b_rne(acc[i][j][rr] + bv);
        }
    }
}

// ---------------------------------------------------------------------------
// Scan v4 (xproj path). 64 blocks x 512 thr (8 waves). Block b owns units
// [16b,16b+16); wave w: gate g=w&3, K-half kh=w>>2 (16 reg-resident W_hh
// B-frags). Per step:
//   1. cooperative stage: full 64 KB h-state global -> LDS, 8x dwordx4 per
//      thread issued back-to-back (full MLP: 1 parallel L3 round trip instead
//      of the register-starved serialized per-wave loads of v3). XOR-swizzled
//      LDS layout (byte ^= ((b&7)<<4)) => both ds_write_b128 staging and
//      ds_read_b128 frag loads are bank-uniform (8 lanes/16B-slot = floor).
//      Also removes the 4x gate-redundant global re-reads (256KB -> 64KB/blk).
//   2. h-GEMM from LDS, LDS K-half reduce, elementwise.
//   3. release fence + flag store; out[] stores + next-step xproj prefetch are
//      issued INSIDE the flag->poll window so they hide under the barrier.
// ---------------------------------------------------------------------------
__launch_bounds__(512, 2)
__global__ void lstm_scan_xp(const ushort_t* __restrict__ xproj, // [16384][4096] bf16
                             const ushort_t* __restrict__ wthh,  // [4096][1024] bf16
                             ushort_t* __restrict__ h0buf,       // bf16 frag-layout
                             ushort_t* __restrict__ h1buf,
                             float* __restrict__ out,            // f32: hseq|h_T|c_T
                             uint32* __restrict__ flags)         // 64, stride 16
{
    const int tid  = threadIdx.x;
    const int bid  = blockIdx.x;
    const int wave = tid >> 6, lane = tid & 63, l16 = lane & 15, quad = lane >> 4;
    const int g     = wave & 3;
    const int khalf = wave >> 2;
    const int unit0 = bid * 16;
    const int col0  = g * 1024 + unit0 + l16;

    __shared__ ushort_t hs[32 * 1024];   // staged h-state, XOR-swizzled (64 KB)
    __shared__ float gA[4 * 32 * 17];
    __shared__ float gB[4 * 32 * 17];

    // one-time: W_hh B-frags from transposed bf16 weights (16B vector loads)
    short8 whf[16];
#pragma unroll
    for (int kk = 0; kk < 16; kk++)
        whf[kk] = *(const short8*)(wthh + (size_t)col0 * 1024 + khalf * 512 + kk * 32 + quad * 8);

    const int eb = tid >> 4, ej = tid & 15;
    const int hwoff = (bid >> 1) * 1024 + eb * 32 + 16 * (bid & 1) + ej; // frag layout
    float cst = 0.f;

    // swizzled LDS byte offsets for the two A-frag reads of this lane.
    // linear byte = row*2048 + b*64 + quad*16 ; swizzle XORs bits 4-6 with b&7.
    const int b0 = l16, b1 = l16 + 16;
    const int off0 = (b0 * 64 + quad * 16) ^ ((b0 & 7) << 4);
    const int off1 = (b1 * 64 + quad * 16) ^ ((b1 & 7) << 4);
    const int rowbase = khalf * 16 * 2048;   // byte offset of this wave's K-half

    // prefetch xproj gate values for t=0
    ushort_t xq[4];
    {
        const ushort_t* xp = xproj + ((size_t)eb * T_ + 0) * G4_ + unit0 + ej;
#pragma unroll
        for (int gg = 0; gg < 4; gg++) xq[gg] = xp[gg * 1024];
    }

    for (int t = 0; t < 512; t++) {
        const ushort_t* hr = (t & 1) ? h1buf : h0buf;
        ushort_t*       hw = (t & 1) ? h0buf : h1buf;

        // ---- 1. cooperative stage h -> LDS (swizzled), 8 x 16B per thread
        {
            const uint4* src = (const uint4*)hr;
#pragma unroll
            for (int r = 0; r < 8; r++) {
                const int c   = r * 512 + tid;                    // 16B chunk id
                const int dst = (c * 16) ^ (((c >> 2) & 7) << 4); // same swizzle
                *(uint4*)((char*)hs + dst) = src[c];
            }
        }
        __syncthreads();

        // ---- 2. h-GEMM from LDS (bank-uniform ds_read_b128)
        floatx4 a0a = (floatx4){0.f, 0.f, 0.f, 0.f};
        floatx4 a0b = a0a, a1a = a0a, a1b = a0a;
#pragma unroll
        for (int kk = 0; kk < 16; kk++) {
            const char* base = (const char*)hs + rowbase + kk * 2048;
            const short8 a0 = *(const short8*)(base + off0);
            const short8 a1 = *(const short8*)(base + off1);
            if (kk & 1) {
                a0b = __builtin_amdgcn_mfma_f32_16x16x32_bf16(a0, whf[kk], a0b, 0, 0, 0);
                a1b = __builtin_amdgcn_mfma_f32_16x16x32_bf16(a1, whf[kk], a1b, 0, 0, 0);
            } else {
                a0a = __builtin_amdgcn_mfma_f32_16x16x32_bf16(a0, whf[kk], a0a, 0, 0, 0);
                a1a = __builtin_amdgcn_mfma_f32_16x16x32_bf16(a1, whf[kk], a1a, 0, 0, 0);
            }
        }
        const floatx4 s0 = a0a + a0b;
        const floatx4 s1 = a1a + a1b;
        float* gd = khalf ? gB : gA;
#pragma unroll
        for (int rr = 0; rr < 4; rr++) {
            gd[(g * 32 + quad * 4 + rr) * 17 + l16]      = s0[rr];
            gd[(g * 32 + 16 + quad * 4 + rr) * 17 + l16] = s1[rr];
        }
        __syncthreads();

        // ---- 3. elementwise: thread -> (batch eb, unit ej)
        float hval, cval;
        {
            const float gi = gA[(0 * 32 + eb) * 17 + ej] + gB[(0 * 32 + eb) * 17 + ej] + b2f(xq[0]);
            const float gf = gA[(1 * 32 + eb) * 17 + ej] + gB[(1 * 32 + eb) * 17 + ej] + b2f(xq[1]);
            const float gg = gA[(2 * 32 + eb) * 17 + ej] + gB[(2 * 32 + eb) * 17 + ej] + b2f(xq[2]);
            const float go = gA[(3 * 32 + eb) * 17 + ej] + gB[(3 * 32 + eb) * 17 + ej] + b2f(xq[3]);
            const float iv = sigm(gi);
            const float fv = sigm(gf);
            const float gv = tanh_(gg);
            const float ov = sigm(go);
            cval = fv * cst + iv * gv;
            cst = cval;
            hval = ov * tanh_(cval);
            hw[hwoff] = f2b_rne(hval);   // cross-block h store: must precede flag
        }

        if (t < 511) {
            __syncthreads();   // drain all waves' h stores (vmcnt 0) pre-release

            // parallel arrive: release fence + per-block flag store
            if (tid == 0) {
                __threadfence();
                __hip_atomic_store(&flags[bid * 16], (uint32)(t + 1),
                                   __ATOMIC_RELAXED, __HIP_MEMORY_SCOPE_AGENT);
            }

            // hide out[] store + next-step xproj prefetch under the barrier
            out[((size_t)eb * T_ + t) * H_ + unit0 + ej] = hval;
            {
                const ushort_t* xp = xproj + ((size_t)eb * T_ + (t + 1)) * G4_ + unit0 + ej;
#pragma unroll
                for (int gg = 0; gg < 4; gg++) xq[gg] = xp[gg * 1024];
            }

            // wave 0 polls all 64 flags at once (ballot-reduce)
            if (wave == 0) {
                uint32 v;
                do {
                    v = __hip_atomic_load(&flags[lane * 16],
                                          __ATOMIC_RELAXED, __HIP_MEMORY_SCOPE_AGENT);
                } while (__ballot(v >= (uint32)(t + 1)) != ~0ull);
            }
            if (tid == 0) __threadfence();   // acquire: invalidate, see fresh h
            __syncthreads();
        } else {
            out[((size_t)eb * T_ + t) * H_ + unit0 + ej] = hval;
            out[HSEQ_ + eb * H_ + unit0 + ej] = hval;
            out[HSEQ_ + B_ * H_ + eb * H_ + unit0 + ej] = cval;
        }
    }
}

// ---------------------------------------------------------------------------
// Fallback (ws too small for xproj): R4 kernel, verbatim.
// ---------------------------------------------------------------------------
__launch_bounds__(512, 2)
__global__ void lstm_scan_fused(const float* __restrict__ x,
                                const float* __restrict__ wih,
                                const float* __restrict__ whh,
                                const float* __restrict__ bias,
                                ushort_t* __restrict__ h0buf,
                                ushort_t* __restrict__ h1buf,
                                float* __restrict__ out,
                                uint32* __restrict__ ctr)
{
    const int tid  = threadIdx.x;
    const int bid  = blockIdx.x;
    const int wave = tid >> 6, lane = tid & 63, l16 = lane & 15, quad = lane >> 4;
    const int g     = wave & 3;
    const int khalf = wave >> 2;
    const int unit0 = bid * 16;
    const int col0  = g * 1024 + unit0 + l16;
    const int kbase = khalf * 512;

    __shared__ ushort_t xs[32 * 1024];
    __shared__ float gA[4 * 32 * 17];
    __shared__ float gB[4 * 32 * 17];

    short8 wif[16], whf[16];
#pragma unroll
    for (int kk = 0; kk < 16; kk++) {
        short8 vi, vh;
#pragma unroll
        for (int j = 0; j < 8; j++) {
            const size_t k = (size_t)(kbase + kk * 32 + quad * 8 + j);
            vi[j] = (short)f2b_rne(wih[k * G4_ + col0]);
            vh[j] = (short)f2b_rne(whh[k * G4_ + col0]);
        }
        wif[kk] = vi;
        whf[kk] = vh;
    }
    const float bcol = (khalf == 0) ? bias[col0] : 0.f;

    const int eb = tid >> 4, ej = tid & 15;
    const int hwoff = (bid >> 1) * 1024 + eb * 32 + 16 * (bid & 1) + ej;
    float cst = 0.f;

    floatx4 a0a, a0b, a1a, a1b;

    {
        const int sb = tid >> 4, sc = tid & 15;
        const float* xrow = x + ((size_t)sb * T_ + 0) * H_ + sc * 64;
#pragma unroll
        for (int q = 0; q < 8; q++) {
            const uint4 u0 = *(const uint4*)(xrow + q * 8);
            const uint4 u1 = *(const uint4*)(xrow + q * 8 + 4);
            uint4 p;
            p.x = __builtin_amdgcn_perm(u0.y, u0.x, 0x07060302u);
            p.y = __builtin_amdgcn_perm(u0.w, u0.z, 0x07060302u);
            p.z = __builtin_amdgcn_perm(u1.y, u1.x, 0x07060302u);
            p.w = __builtin_amdgcn_perm(u1.w, u1.z, 0x07060302u);
            const int k = sc * 64 + q * 8;
            *(uint4*)&xs[(k >> 5) * 1024 + sb * 32 + (k & 31)] = p;
        }
    }
    __syncthreads();
    a0a = (floatx4){bcol, bcol, bcol, bcol};
    a1a = a0a;
    a0b = (floatx4){0.f, 0.f, 0.f, 0.f};
    a1b = a0b;
#pragma unroll
    for (int kk = 0; kk < 16; kk++) {
        const ushort_t* ps = &xs[(khalf * 16 + kk) * 1024 + quad * 8];
        const short8 a0 = *(const short8*)(ps + l16 * 32);
        const short8 a1 = *(const short8*)(ps + (16 + l16) * 32);
        if (kk & 1) {
            a0b = __builtin_amdgcn_mfma_f32_16x16x32_bf16(a0, wif[kk], a0b, 0, 0, 0);
            a1b = __builtin_amdgcn_mfma_f32_16x16x32_bf16(a1, wif[kk], a1b, 0, 0, 0);
        } else {
            a0a = __builtin_amdgcn_mfma_f32_16x16x32_bf16(a0, wif[kk], a0a, 0, 0, 0);
            a1a = __builtin_amdgcn_mfma_f32_16x16x32_bf16(a1, wif[kk], a1a, 0, 0, 0);
        }
    }

    for (int t = 0; t < 512; t++) {
        const ushort_t* hr = (t & 1) ? h1buf : h0buf;
        ushort_t*       hw = (t & 1) ? h0buf : h1buf;

#pragma unroll
        for (int kk = 0; kk < 16; kk++) {
            const ushort_t* pa = hr + (khalf * 16 + kk) * 1024 + quad * 8;
            const short8 a0 = *(const short8*)(pa + l16 * 32);
            const short8 a1 = *(const short8*)(pa + (16 + l16) * 32);
            if (kk & 1) {
                a0b = __builtin_amdgcn_mfma_f32_16x16x32_bf16(a0, whf[kk], a0b, 0, 0, 0);
                a1b = __builtin_amdgcn_mfma_f32_16x16x32_bf16(a1, whf[kk], a1b, 0, 0, 0);
            } else {
                a0a = __builtin_amdgcn_mfma_f32_16x16x32_bf16(a0, whf[kk], a0a, 0, 0, 0);
                a1a = __builtin_amdgcn_mfma_f32_16x16x32_bf16(a1, whf[kk], a1a, 0, 0, 0);
            }
        }
        const floatx4 s0 = a0a + a0b;
        const floatx4 s1 = a1a + a1b;
        float* gd = khalf ? gB : gA;
#pragma unroll
        for (int rr = 0; rr < 4; rr++) {
            gd[(g * 32 + quad * 4 + rr) * 17 + l16]      = s0[rr];
            gd[(g * 32 + 16 + quad * 4 + rr) * 17 + l16] = s1[rr];
        }
        __syncthreads();

        {
            const float gi = gA[(0 * 32 + eb) * 17 + ej] + gB[(0 * 32 + eb) * 17 + ej];
            const float gf = gA[(1 * 32 + eb) * 17 + ej] + gB[(1 * 32 + eb) * 17 + ej];
            const float gg = gA[(2 * 32 + eb) * 17 + ej] + gB[(2 * 32 + eb) * 17 + ej];
            const float go = gA[(3 * 32 + eb) * 17 + ej] + gB[(3 * 32 + eb) * 17 + ej];
            const float iv = sigm(gi);
            const float fv = sigm(gf);
            const float gv = tanh_(gg);
            const float ov = sigm(go);
            const float c = fv * cst + iv * gv;
            cst = c;
            const float h = ov * tanh_(c);
            hw[hwoff] = f2b_rne(h);
            out[((size_t)eb * T_ + t) * H_ + unit0 + ej] = h;
            if (t == 511) {
                out[HSEQ_ + eb * H_ + unit0 + ej] = h;
                out[HSEQ_ + B_ * H_ + eb * H_ + unit0 + ej] = cst;
            }
        }
        __syncthreads();

        if (t < 511) {
            if (tid == 0) {
                __threadfence();
                __hip_atomic_fetch_add(ctr, 1u, __ATOMIC_RELAXED, __HIP_MEMORY_SCOPE_AGENT);
            }
            {
                const int sb = tid >> 4, sc = tid & 15;
                const float* xrow = x + ((size_t)sb * T_ + (t + 1)) * H_ + sc * 64;
#pragma unroll
                for (int q = 0; q < 8; q++) {
                    const uint4 u0 = *(const uint4*)(xrow + q * 8);
                    const uint4 u1 = *(const uint4*)(xrow + q * 8 + 4);
                    uint4 p;
                    p.x = __builtin_amdgcn_perm(u0.y, u0.x, 0x07060302u);
                    p.y = __builtin_amdgcn_perm(u0.w, u0.z, 0x07060302u);
                    p.z = __builtin_amdgcn_perm(u1.y, u1.x, 0x07060302u);
                    p.w = __builtin_amdgcn_perm(u1.w, u1.z, 0x07060302u);
                    const int k = sc * 64 + q * 8;
                    *(uint4*)&xs[(k >> 5) * 1024 + sb * 32 + (k & 31)] = p;
                }
            }
            __syncthreads();
            a0a = (floatx4){bcol, bcol, bcol, bcol};
            a1a = a0a;
            a0b = (floatx4){0.f, 0.f, 0.f, 0.f};
            a1b = a0b;
#pragma unroll
            for (int kk = 0; kk < 16; kk++) {
                const ushort_t* ps = &xs[(khalf * 16 + kk) * 1024 + quad * 8];
                const short8 a0 = *(const short8*)(ps + l16 * 32);
                const short8 a1 = *(const short8*)(ps + (16 + l16) * 32);
                if (kk & 1) {
                    a0b = __builtin_amdgcn_mfma_f32_16x16x32_bf16(a0, wif[kk], a0b, 0, 0, 0);
                    a1b = __builtin_amdgcn_mfma_f32_16x16x32_bf16(a1, wif[kk], a1b, 0, 0, 0);
                } else {
                    a0a = __builtin_amdgcn_mfma_f32_16x16x32_bf16(a0, wif[kk], a0a, 0, 0, 0);
                    a1a = __builtin_amdgcn_mfma_f32_16x16x32_bf16(a1, wif[kk], a1a, 0, 0, 0);
                }
            }
            if (tid == 0) {
                const uint32 target = (uint32)NBLK * (uint32)(t + 1);
                while (__hip_atomic_load(ctr, __ATOMIC_RELAXED, __HIP_MEMORY_SCOPE_AGENT) < target) {
                    __builtin_amdgcn_s_sleep(1);
                }
                __threadfence();
            }
            __syncthreads();
        }
    }
}

// ---------------------------------------------------------------------------
extern "C" void kernel_launch(void* const* d_in, const int* in_sizes, int n_in,
                              void* d_out, int out_size, void* d_ws, size_t ws_size,
                              hipStream_t stream)
{
    const float* x    = (const float*)d_in[0];  // [32,512,1024] f32
    const float* wih  = (const float*)d_in[1];  // [1024,4096] f32
    const float* whh  = (const float*)d_in[2];  // [1024,4096] f32
    const float* bias = (const float*)d_in[3];  // [4096] f32
    float* out = (float*)d_out;
    char* ws = (char*)d_ws;

    if (ws_size >= WS_NEED) {
        ushort_t* xproj = (ushort_t*)(ws + XPROJ_OFF);
        ushort_t* wtih  = (ushort_t*)(ws + WTIH_OFF);
        ushort_t* wthh  = (ushort_t*)(ws + WTHH_OFF);
        ushort_t* h0    = (ushort_t*)(ws + H0X_OFF);
        ushort_t* h1    = (ushort_t*)(ws + H1X_OFF);
        uint32*   flags = (uint32*)(ws + FLAGS_OFF);

        hipMemsetAsync(ws + H0X_OFF, 0, 2 * 65536 + 4096, stream);
        hipLaunchKernelGGL(transpose_cvt, dim3(2048), dim3(256), 0, stream, wih, wtih);
        hipLaunchKernelGGL(transpose_cvt, dim3(2048), dim3(256), 0, stream, whh, wthh);
        hipLaunchKernelGGL(gemm_xproj, dim3(32, 128), dim3(256), 0, stream,
                           x, wtih, bias, xproj);
        hipLaunchKernelGGL(lstm_scan_xp, dim3(NBLK), dim3(512), 0, stream,
                           xproj, wthh, h0, h1, out, flags);
    } else {
        ushort_t* h0  = (ushort_t*)(ws + H0_OFF);
        ushort_t* h1  = (ushort_t*)(ws + H1_OFF);
        uint32*   ctr = (uint32*)(ws + CTR_OFF);

        hipMemsetAsync(ws, 0, 131072 + 256, stream);
        hipLaunchKernelGGL(lstm_scan_fused, dim3(NBLK), dim3(512), 0, stream,
                           x, wih, whh, bias, h0, h1, out, ctr);
    }
}

// Round 2
// 2457.832 us; speedup vs baseline: 2.3898x; 1.5225x over previous
//
#include <hip/hip_runtime.h>

typedef unsigned short ushort_t;
typedef unsigned int   uint32;
typedef unsigned long long ull_t;
typedef __attribute__((ext_vector_type(8))) short short8;   // 8 x bf16 (4 VGPRs)
typedef __attribute__((ext_vector_type(4))) float floatx4;  // MFMA 16x16 accum

#define B_    32
#define T_    512
#define H_    1024
#define G4_   4096
#define HSEQ_ (B_*T_*H_)     // 16777216

#define NBLK 64

// ---- ws layout, xproj path (requires ws_size >= WS_NEED) ----
#define XPROJ_OFF 0ul                 // bf16 [16384][4096] = 134217728
#define WTIH_OFF  134217728ul         // bf16 [4096][1024]  = 8388608
#define WTHH_OFF  142606336ul         // bf16 [4096][1024]  = 8388608
#define H0X_OFF   150994944ul         // bf16 frag-layout   = 65536
#define H1X_OFF   151060480ul         // bf16 frag-layout   = 65536
#define FLAGS_OFF 151126016ul         // 64 x uint32, 64B-padded = 4096
#define WS_NEED   151130112ul

// ---- ws layout, fallback path (R4) ----
#define H0_OFF  0ul
#define H1_OFF  65536ul
#define CTR_OFF 131072ul

__device__ __forceinline__ ushort_t f2b_rne(float f) {
    uint32 u = __float_as_uint(f);
    u += 0x7fffu + ((u >> 16) & 1u);      // round-to-nearest-even
    return (ushort_t)(u >> 16);
}
__device__ __forceinline__ float b2f(ushort_t u) { return __uint_as_float(((uint32)u) << 16); }
__device__ __forceinline__ float sigm(float x)  { return 1.f / (1.f + __expf(-x)); }
__device__ __forceinline__ float tanh_(float x) { return 1.f - 2.f / (__expf(2.f * x) + 1.f); }

// ---------------------------------------------------------------------------
// Transpose+convert: in fp32 [1024 k][4096 n] -> out bf16 [4096 n][1024 k].
// ---------------------------------------------------------------------------
__global__ void transpose_cvt(const float* __restrict__ in, ushort_t* __restrict__ out)
{
    const int id = blockIdx.x * 256 + threadIdx.x;    // 524288 total
    const int n  = id & 4095;
    const int k0 = (id >> 12) * 8;
    union { ushort_t v[8]; uint4 q; } r;
#pragma unroll
    for (int j = 0; j < 8; j++)
        r.v[j] = f2b_rne(in[(size_t)(k0 + j) * G4_ + n]);
    *(uint4*)(out + (size_t)n * 1024 + k0) = r.q;
}

// ---------------------------------------------------------------------------
// xproj GEMM: xproj[m][n] = bf16( sum_k x[m][k]*W_ih[k][n] + bias[n] )
// ---------------------------------------------------------------------------
__launch_bounds__(256, 2)
__global__ void gemm_xproj(const float* __restrict__ A, const ushort_t* __restrict__ Bt,
                           const float* __restrict__ bias, ushort_t* __restrict__ C)
{
    __shared__ ushort_t As[128 * 32];
    __shared__ ushort_t Bs[128 * 32];
    const int tid = threadIdx.x;
    const int wave = tid >> 6, lane = tid & 63, l16 = lane & 15, quad = lane >> 4;
    const int wm = (wave >> 1) * 64, wn = (wave & 1) * 64;
    const int m0 = blockIdx.y * 128, n0 = blockIdx.x * 128;
    const int r = tid >> 2;               // 0..63 (staging row)
    const int kp = (tid & 3) * 8;         // 0..24 step 8

    floatx4 acc[4][4];
#pragma unroll
    for (int i = 0; i < 4; i++)
#pragma unroll
        for (int j = 0; j < 4; j++) acc[i][j] = (floatx4){0.f, 0.f, 0.f, 0.f};

    for (int kk = 0; kk < 1024; kk += 32) {
#pragma unroll
        for (int h = 0; h < 2; h++) {
            const float* ap = A + (size_t)(m0 + r + h * 64) * 1024 + kk + kp;
            const uint4 u0 = *(const uint4*)ap;
            const uint4 u1 = *(const uint4*)(ap + 4);
            uint4 p;
            p.x = __builtin_amdgcn_perm(u0.y, u0.x, 0x07060302u);
            p.y = __builtin_amdgcn_perm(u0.w, u0.z, 0x07060302u);
            p.z = __builtin_amdgcn_perm(u1.y, u1.x, 0x07060302u);
            p.w = __builtin_amdgcn_perm(u1.w, u1.z, 0x07060302u);
            *(uint4*)&As[(r + h * 64) * 32 + kp] = p;
        }
        const ushort_t* bp = Bt + (size_t)(n0 + r) * 1024 + kk + kp;
        *(uint4*)&Bs[r * 32 + kp]        = *(const uint4*)bp;
        *(uint4*)&Bs[(r + 64) * 32 + kp] = *(const uint4*)(bp + 64 * 1024);
        __syncthreads();

        short8 af[4], bfr[4];
#pragma unroll
        for (int i = 0; i < 4; i++) af[i]  = *(const short8*)&As[(wm + i * 16 + l16) * 32 + quad * 8];
#pragma unroll
        for (int j = 0; j < 4; j++) bfr[j] = *(const short8*)&Bs[(wn + j * 16 + l16) * 32 + quad * 8];
#pragma unroll
        for (int i = 0; i < 4; i++)
#pragma unroll
            for (int j = 0; j < 4; j++)
                acc[i][j] = __builtin_amdgcn_mfma_f32_16x16x32_bf16(af[i], bfr[j], acc[i][j], 0, 0, 0);
        __syncthreads();
    }

#pragma unroll
    for (int i = 0; i < 4; i++) {
        const int gm = m0 + wm + i * 16 + quad * 4;
#pragma unroll
        for (int j = 0; j < 4; j++) {
            const int gn = n0 + wn + j * 16 + l16;
            const float bv = bias[gn];
#pragma unroll
            for (int rr = 0; rr < 4; rr++)
                C[(size_t)(gm + rr) * G4_ + gn] = f2b_rne(acc[i][j][rr] + bv);
        }
    }
}

// ---------------------------------------------------------------------------
// Scan v5 (xproj path). 64 blocks x 512 thr (8 waves). Block b owns units
// [16b,16b+16); wave w: gate g=w&3, K-half kh=w>>2. Coherence-point protocol:
// ALL cross-block traffic (h state, flags) uses agent-scope atomics, which
// bypass L1/L2 to L3 (the common coherence point across XCDs). No
// __threadfence at all => no per-step buffer_wbl2 (L2 writeback) and no L2
// invalidate. Per step:
//   1. per-wave fine-grained arrival: wave w polls ONLY its 8 source blocks'
//      flags (one parallel ballot sweep = one L3 round trip), then stages its
//      8 x 1KB chunks with all 16 u64 agent-loads issued back-to-back (full
//      MLP, ~1 L3 round trip) into the XOR-swizzled LDS h image.
//   2. h-GEMM from LDS, K-half LDS reduce, elementwise.
//   3. h store = packed uint32 agent-scope atomic store (pair lanes via
//      shfl_xor); __syncthreads' implicit vmcnt(0) drains it; tid0 then
//      publishes the flag (relaxed agent). out[] store + next-step xproj
//      prefetch issue after the flag, hiding under the other blocks' polls.
// ---------------------------------------------------------------------------
__launch_bounds__(512, 2)
__global__ void lstm_scan_xp(const ushort_t* __restrict__ xproj, // [16384][4096] bf16
                             const ushort_t* __restrict__ wthh,  // [4096][1024] bf16
                             ushort_t* __restrict__ h0buf,       // bf16 frag-layout
                             ushort_t* __restrict__ h1buf,
                             float* __restrict__ out,            // f32: hseq|h_T|c_T
                             uint32* __restrict__ flags)         // 64, stride 16
{
    const int tid  = threadIdx.x;
    const int bid  = blockIdx.x;
    const int wave = tid >> 6, lane = tid & 63, l16 = lane & 15, quad = lane >> 4;
    const int g     = wave & 3;
    const int khalf = wave >> 2;
    const int unit0 = bid * 16;
    const int col0  = g * 1024 + unit0 + l16;

    __shared__ ushort_t hs[32 * 1024];   // staged h-state, XOR-swizzled (64 KB)
    __shared__ float gA[4 * 32 * 17];
    __shared__ float gB[4 * 32 * 17];

    // one-time: W_hh B-frags from transposed bf16 weights (16B vector loads)
    short8 whf[16];
#pragma unroll
    for (int kk = 0; kk < 16; kk++)
        whf[kk] = *(const short8*)(wthh + (size_t)col0 * 1024 + khalf * 512 + kk * 32 + quad * 8);

    const int eb = tid >> 4, ej = tid & 15;
    const int hwoff = (bid >> 1) * 1024 + eb * 32 + 16 * (bid & 1) + ej; // frag layout
    float cst = 0.f;

    // swizzled LDS byte offsets for the two A-frag reads of this lane.
    const int b0 = l16, b1 = l16 + 16;
    const int off0 = (b0 * 64 + quad * 16) ^ ((b0 & 7) << 4);
    const int off1 = (b1 * 64 + quad * 16) ^ ((b1 & 7) << 4);
    const int rowbase = khalf * 16 * 2048;   // byte offset of this wave's K-half

    // staging geometry: wave w stages source blocks [8w, 8w+8). Source S's
    // 1KB lives at bytes (S>>1)*2048 + eb*64 + (S&1)*32 + half*16 ; lane ->
    // (eb = lane>>1, half = lane&1).
    const int src0  = wave * 8;
    const int abase = (lane >> 1) * 64 + (lane & 1) * 16;

    // prefetch xproj gate values for t=0
    ushort_t xq[4];
    {
        const ushort_t* xp = xproj + ((size_t)eb * T_ + 0) * G4_ + unit0 + ej;
#pragma unroll
        for (int gg = 0; gg < 4; gg++) xq[gg] = xp[gg * 1024];
    }

    for (int t = 0; t < 512; t++) {
        const ushort_t* hr = (t & 1) ? h1buf : h0buf;
        ushort_t*       hw = (t & 1) ? h0buf : h1buf;

        // ---- 1a. wait for this wave's 8 source blocks (h_t published)
        for (;;) {
            int rdy = 1;
            if (lane < 8)
                rdy = (__hip_atomic_load(&flags[(src0 + lane) * 16],
                                         __ATOMIC_RELAXED, __HIP_MEMORY_SCOPE_AGENT)
                       >= (uint32)t);
            if (__ballot(rdy) == ~0ull) break;
        }

        // ---- 1b. stage 8 x 1KB: issue all 16 agent-loads, then LDS writes
        {
            ull_t d0[8], d1[8];
#pragma unroll
            for (int sl = 0; sl < 8; sl++) {
                const int S = src0 + sl;
                const size_t a = (size_t)(S >> 1) * 2048 + (size_t)((S & 1) * 32 + abase);
                const char* p = (const char*)hr + a;
                d0[sl] = __hip_atomic_load((const ull_t*)p,
                                           __ATOMIC_RELAXED, __HIP_MEMORY_SCOPE_AGENT);
                d1[sl] = __hip_atomic_load((const ull_t*)(p + 8),
                                           __ATOMIC_RELAXED, __HIP_MEMORY_SCOPE_AGENT);
            }
#pragma unroll
            for (int sl = 0; sl < 8; sl++) {
                const int S = src0 + sl;
                const int c = ((S >> 1) * 2048 + (S & 1) * 32 + abase) >> 4;
                const int dst = (c * 16) ^ (((c >> 2) & 7) << 4);
                uint4 v;
                *(ull_t*)&v.x = d0[sl];
                *(ull_t*)&v.z = d1[sl];
                *(uint4*)((char*)hs + dst) = v;
            }
        }
        __syncthreads();

        // ---- 2. h-GEMM from LDS (bank-uniform ds_read_b128)
        floatx4 a0a = (floatx4){0.f, 0.f, 0.f, 0.f};
        floatx4 a0b = a0a, a1a = a0a, a1b = a0a;
#pragma unroll
        for (int kk = 0; kk < 16; kk++) {
            const char* base = (const char*)hs + rowbase + kk * 2048;
            const short8 a0 = *(const short8*)(base + off0);
            const short8 a1 = *(const short8*)(base + off1);
            if (kk & 1) {
                a0b = __builtin_amdgcn_mfma_f32_16x16x32_bf16(a0, whf[kk], a0b, 0, 0, 0);
                a1b = __builtin_amdgcn_mfma_f32_16x16x32_bf16(a1, whf[kk], a1b, 0, 0, 0);
            } else {
                a0a = __builtin_amdgcn_mfma_f32_16x16x32_bf16(a0, whf[kk], a0a, 0, 0, 0);
                a1a = __builtin_amdgcn_mfma_f32_16x16x32_bf16(a1, whf[kk], a1a, 0, 0, 0);
            }
        }
        const floatx4 s0 = a0a + a0b;
        const floatx4 s1 = a1a + a1b;
        float* gd = khalf ? gB : gA;
#pragma unroll
        for (int rr = 0; rr < 4; rr++) {
            gd[(g * 32 + quad * 4 + rr) * 17 + l16]      = s0[rr];
            gd[(g * 32 + 16 + quad * 4 + rr) * 17 + l16] = s1[rr];
        }
        __syncthreads();

        // ---- 3. elementwise: thread -> (batch eb, unit ej)
        float hval, cval;
        {
            const float gi = gA[(0 * 32 + eb) * 17 + ej] + gB[(0 * 32 + eb) * 17 + ej] + b2f(xq[0]);
            const float gf = gA[(1 * 32 + eb) * 17 + ej] + gB[(1 * 32 + eb) * 17 + ej] + b2f(xq[1]);
            const float gg = gA[(2 * 32 + eb) * 17 + ej] + gB[(2 * 32 + eb) * 17 + ej] + b2f(xq[2]);
            const float go = gA[(3 * 32 + eb) * 17 + ej] + gB[(3 * 32 + eb) * 17 + ej] + b2f(xq[3]);
            const float iv = sigm(gi);
            const float fv = sigm(gf);
            const float gv = tanh_(gg);
            const float ov = sigm(go);
            cval = fv * cst + iv * gv;
            cst = cval;
            hval = ov * tanh_(cval);
        }

        // pack pair (ej, ej+1) into one uint32 agent-scope store (bypasses L2)
        {
            const uint32 myb = (uint32)f2b_rne(hval);
            const uint32 nbb = (uint32)__shfl_xor((int)myb, 1);
            if ((ej & 1) == 0)
                __hip_atomic_store((uint32*)(hw + hwoff), myb | (nbb << 16),
                                   __ATOMIC_RELAXED, __HIP_MEMORY_SCOPE_AGENT);
        }

        if (t < 511) {
            __syncthreads();   // implicit vmcnt(0): all waves' h stores complete
            if (tid == 0)
                __hip_atomic_store(&flags[bid * 16], (uint32)(t + 1),
                                   __ATOMIC_RELAXED, __HIP_MEMORY_SCOPE_AGENT);
            // hide out[] store + next-step xproj prefetch under others' polls
            out[((size_t)eb * T_ + t) * H_ + unit0 + ej] = hval;
            {
                const ushort_t* xp = xproj + ((size_t)eb * T_ + (t + 1)) * G4_ + unit0 + ej;
#pragma unroll
                for (int gg = 0; gg < 4; gg++) xq[gg] = xp[gg * 1024];
            }
        } else {
            out[((size_t)eb * T_ + t) * H_ + unit0 + ej] = hval;
            out[HSEQ_ + eb * H_ + unit0 + ej] = hval;
            out[HSEQ_ + B_ * H_ + eb * H_ + unit0 + ej] = cval;
        }
    }
}

// ---------------------------------------------------------------------------
// Fallback (ws too small for xproj): R4 kernel, verbatim.
// ---------------------------------------------------------------------------
__launch_bounds__(512, 2)
__global__ void lstm_scan_fused(const float* __restrict__ x,
                                const float* __restrict__ wih,
                                const float* __restrict__ whh,
                                const float* __restrict__ bias,
                                ushort_t* __restrict__ h0buf,
                                ushort_t* __restrict__ h1buf,
                                float* __restrict__ out,
                                uint32* __restrict__ ctr)
{
    const int tid  = threadIdx.x;
    const int bid  = blockIdx.x;
    const int wave = tid >> 6, lane = tid & 63, l16 = lane & 15, quad = lane >> 4;
    const int g     = wave & 3;
    const int khalf = wave >> 2;
    const int unit0 = bid * 16;
    const int col0  = g * 1024 + unit0 + l16;
    const int kbase = khalf * 512;

    __shared__ ushort_t xs[32 * 1024];
    __shared__ float gA[4 * 32 * 17];
    __shared__ float gB[4 * 32 * 17];

    short8 wif[16], whf[16];
#pragma unroll
    for (int kk = 0; kk < 16; kk++) {
        short8 vi, vh;
#pragma unroll
        for (int j = 0; j < 8; j++) {
            const size_t k = (size_t)(kbase + kk * 32 + quad * 8 + j);
            vi[j] = (short)f2b_rne(wih[k * G4_ + col0]);
            vh[j] = (short)f2b_rne(whh[k * G4_ + col0]);
        }
        wif[kk] = vi;
        whf[kk] = vh;
    }
    const float bcol = (khalf == 0) ? bias[col0] : 0.f;

    const int eb = tid >> 4, ej = tid & 15;
    const int hwoff = (bid >> 1) * 1024 + eb * 32 + 16 * (bid & 1) + ej;
    float cst = 0.f;

    floatx4 a0a, a0b, a1a, a1b;

    {
        const int sb = tid >> 4, sc = tid & 15;
        const float* xrow = x + ((size_t)sb * T_ + 0) * H_ + sc * 64;
#pragma unroll
        for (int q = 0; q < 8; q++) {
            const uint4 u0 = *(const uint4*)(xrow + q * 8);
            const uint4 u1 = *(const uint4*)(xrow + q * 8 + 4);
            uint4 p;
            p.x = __builtin_amdgcn_perm(u0.y, u0.x, 0x07060302u);
            p.y = __builtin_amdgcn_perm(u0.w, u0.z, 0x07060302u);
            p.z = __builtin_amdgcn_perm(u1.y, u1.x, 0x07060302u);
            p.w = __builtin_amdgcn_perm(u1.w, u1.z, 0x07060302u);
            const int k = sc * 64 + q * 8;
            *(uint4*)&xs[(k >> 5) * 1024 + sb * 32 + (k & 31)] = p;
        }
    }
    __syncthreads();
    a0a = (floatx4){bcol, bcol, bcol, bcol};
    a1a = a0a;
    a0b = (floatx4){0.f, 0.f, 0.f, 0.f};
    a1b = a0b;
#pragma unroll
    for (int kk = 0; kk < 16; kk++) {
        const ushort_t* ps = &xs[(khalf * 16 + kk) * 1024 + quad * 8];
        const short8 a0 = *(const short8*)(ps + l16 * 32);
        const short8 a1 = *(const short8*)(ps + (16 + l16) * 32);
        if (kk & 1) {
            a0b = __builtin_amdgcn_mfma_f32_16x16x32_bf16(a0, wif[kk], a0b, 0, 0, 0);
            a1b = __builtin_amdgcn_mfma_f32_16x16x32_bf16(a1, wif[kk], a1b, 0, 0, 0);
        } else {
            a0a = __builtin_amdgcn_mfma_f32_16x16x32_bf16(a0, wif[kk], a0a, 0, 0, 0);
            a1a = __builtin_amdgcn_mfma_f32_16x16x32_bf16(a1, wif[kk], a1a, 0, 0, 0);
        }
    }

    for (int t = 0; t < 512; t++) {
        const ushort_t* hr = (t & 1) ? h1buf : h0buf;
        ushort_t*       hw = (t & 1) ? h0buf : h1buf;

#pragma unroll
        for (int kk = 0; kk < 16; kk++) {
            const ushort_t* pa = hr + (khalf * 16 + kk) * 1024 + quad * 8;
            const short8 a0 = *(const short8*)(pa + l16 * 32);
            const short8 a1 = *(const short8*)(pa + (16 + l16) * 32);
            if (kk & 1) {
                a0b = __builtin_amdgcn_mfma_f32_16x16x32_bf16(a0, whf[kk], a0b, 0, 0, 0);
                a1b = __builtin_amdgcn_mfma_f32_16x16x32_bf16(a1, whf[kk], a1b, 0, 0, 0);
            } else {
                a0a = __builtin_amdgcn_mfma_f32_16x16x32_bf16(a0, whf[kk], a0a, 0, 0, 0);
                a1a = __builtin_amdgcn_mfma_f32_16x16x32_bf16(a1, whf[kk], a1a, 0, 0, 0);
            }
        }
        const floatx4 s0 = a0a + a0b;
        const floatx4 s1 = a1a + a1b;
        float* gd = khalf ? gB : gA;
#pragma unroll
        for (int rr = 0; rr < 4; rr++) {
            gd[(g * 32 + quad * 4 + rr) * 17 + l16]      = s0[rr];
            gd[(g * 32 + 16 + quad * 4 + rr) * 17 + l16] = s1[rr];
        }
        __syncthreads();

        {
            const float gi = gA[(0 * 32 + eb) * 17 + ej] + gB[(0 * 32 + eb) * 17 + ej];
            const float gf = gA[(1 * 32 + eb) * 17 + ej] + gB[(1 * 32 + eb) * 17 + ej];
            const float gg = gA[(2 * 32 + eb) * 17 + ej] + gB[(2 * 32 + eb) * 17 + ej];
            const float go = gA[(3 * 32 + eb) * 17 + ej] + gB[(3 * 32 + eb) * 17 + ej];
            const float iv = sigm(gi);
            const float fv = sigm(gf);
            const float gv = tanh_(gg);
            const float ov = sigm(go);
            const float c = fv * cst + iv * gv;
            cst = c;
            const float h = ov * tanh_(c);
            hw[hwoff] = f2b_rne(h);
            out[((size_t)eb * T_ + t) * H_ + unit0 + ej] = h;
            if (t == 511) {
                out[HSEQ_ + eb * H_ + unit0 + ej] = h;
                out[HSEQ_ + B_ * H_ + eb * H_ + unit0 + ej] = cst;
            }
        }
        __syncthreads();

        if (t < 511) {
            if (tid == 0) {
                __threadfence();
                __hip_atomic_fetch_add(ctr, 1u, __ATOMIC_RELAXED, __HIP_MEMORY_SCOPE_AGENT);
            }
            {
                const int sb = tid >> 4, sc = tid & 15;
                const float* xrow = x + ((size_t)sb * T_ + (t + 1)) * H_ + sc * 64;
#pragma unroll
                for (int q = 0; q < 8; q++) {
                    const uint4 u0 = *(const uint4*)(xrow + q * 8);
                    const uint4 u1 = *(const uint4*)(xrow + q * 8 + 4);
                    uint4 p;
                    p.x = __builtin_amdgcn_perm(u0.y, u0.x, 0x07060302u);
                    p.y = __builtin_amdgcn_perm(u0.w, u0.z, 0x07060302u);
                    p.z = __builtin_amdgcn_perm(u1.y, u1.x, 0x07060302u);
                    p.w = __builtin_amdgcn_perm(u1.w, u1.z, 0x07060302u);
                    const int k = sc * 64 + q * 8;
                    *(uint4*)&xs[(k >> 5) * 1024 + sb * 32 + (k & 31)] = p;
                }
            }
            __syncthreads();
            a0a = (floatx4){bcol, bcol, bcol, bcol};
            a1a = a0a;
            a0b = (floatx4){0.f, 0.f, 0.f, 0.f};
            a1b = a0b;
#pragma unroll
            for (int kk = 0; kk < 16; kk++) {
                const ushort_t* ps = &xs[(khalf * 16 + kk) * 1024 + quad * 8];
                const short8 a0 = *(const short8*)(ps + l16 * 32);
                const short8 a1 = *(const short8*)(ps + (16 + l16) * 32);
                if (kk & 1) {
                    a0b = __builtin_amdgcn_mfma_f32_16x16x32_bf16(a0, wif[kk], a0b, 0, 0, 0);
                    a1b = __builtin_amdgcn_mfma_f32_16x16x32_bf16(a1, wif[kk], a1b, 0, 0, 0);
                } else {
                    a0a = __builtin_amdgcn_mfma_f32_16x16x32_bf16(a0, wif[kk], a0a, 0, 0, 0);
                    a1a = __builtin_amdgcn_mfma_f32_16x16x32_bf16(a1, wif[kk], a1a, 0, 0, 0);
                }
            }
            if (tid == 0) {
                const uint32 target = (uint32)NBLK * (uint32)(t + 1);
                while (__hip_atomic_load(ctr, __ATOMIC_RELAXED, __HIP_MEMORY_SCOPE_AGENT) < target) {
                    __builtin_amdgcn_s_sleep(1);
                }
                __threadfence();
            }
            __syncthreads();
        }
    }
}

// ---------------------------------------------------------------------------
extern "C" void kernel_launch(void* const* d_in, const int* in_sizes, int n_in,
                              void* d_out, int out_size, void* d_ws, size_t ws_size,
                              hipStream_t stream)
{
    const float* x    = (const float*)d_in[0];  // [32,512,1024] f32
    const float* wih  = (const float*)d_in[1];  // [1024,4096] f32
    const float* whh  = (const float*)d_in[2];  // [1024,4096] f32
    const float* bias = (const float*)d_in[3];  // [4096] f32
    float* out = (float*)d_out;
    char* ws = (char*)d_ws;

    if (ws_size >= WS_NEED) {
        ushort_t* xproj = (ushort_t*)(ws + XPROJ_OFF);
        ushort_t* wtih  = (ushort_t*)(ws + WTIH_OFF);
        ushort_t* wthh  = (ushort_t*)(ws + WTHH_OFF);
        ushort_t* h0    = (ushort_t*)(ws + H0X_OFF);
        ushort_t* h1    = (ushort_t*)(ws + H1X_OFF);
        uint32*   flags = (uint32*)(ws + FLAGS_OFF);

        hipMemsetAsync(ws + H0X_OFF, 0, 2 * 65536 + 4096, stream);
        hipLaunchKernelGGL(transpose_cvt, dim3(2048), dim3(256), 0, stream, wih, wtih);
        hipLaunchKernelGGL(transpose_cvt, dim3(2048), dim3(256), 0, stream, whh, wthh);
        hipLaunchKernelGGL(gemm_xproj, dim3(32, 128), dim3(256), 0, stream,
                           x, wtih, bias, xproj);
        hipLaunchKernelGGL(lstm_scan_xp, dim3(NBLK), dim3(512), 0, stream,
                           xproj, wthh, h0, h1, out, flags);
    } else {
        ushort_t* h0  = (ushort_t*)(ws + H0_OFF);
        ushort_t* h1  = (ushort_t*)(ws + H1_OFF);
        uint32*   ctr = (uint32*)(ws + CTR_OFF);

        hipMemsetAsync(ws, 0, 131072 + 256, stream);
        hipLaunchKernelGGL(lstm_scan_fused, dim3(NBLK), dim3(512), 0, stream,
                           x, wih, whh, bias, h0, h1, out, ctr);
    }
}